// Round 7
// baseline (86.470 us; speedup 1.0000x reference)
//
#include <hip/hip_runtime.h>

#define B_   4
#define NQ_  1024
#define NK_  1024
#define H_   8
#define DM_  512

typedef unsigned short us;
typedef unsigned long long ull;
typedef __attribute__((ext_vector_type(8))) short  short8;
typedef __attribute__((ext_vector_type(4))) float  f32x4;
typedef __attribute__((ext_vector_type(4))) int    i32x4;
typedef __attribute__((address_space(3))) unsigned int       lds_u32;
typedef const __attribute__((address_space(1))) unsigned int gl_u32;

static __device__ __forceinline__ us f2bf(float f) {
    unsigned int u = __builtin_bit_cast(unsigned int, f);
    u += 0x7FFF + ((u >> 16) & 1);
    return (us)(u >> 16);
}

// ---------------------------------------------------------------------------
// wprep: weights f32[K][N] -> bf16 [N][K].  256 blocks.
// ---------------------------------------------------------------------------
__global__ __launch_bounds__(256) void wprep(
    const float* __restrict__ wq, const float* __restrict__ wkv,
    const float* __restrict__ wp,
    us* __restrict__ Wq_t, us* __restrict__ Wkv_t, us* __restrict__ Wp_t)
{
    const int t = blockIdx.x, tid = threadIdx.x;
    const float* src; us* dst; int k0, n0, N; const int K = 512;
    if (t < 64)       { src = wq;  dst = Wq_t;  N = 512;  k0 = (t >> 3) * 64;         n0 = (t & 7) * 64; }
    else if (t < 192) { src = wkv; dst = Wkv_t; N = 1024; k0 = ((t - 64) >> 4) * 64;  n0 = ((t - 64) & 15) * 64; }
    else              { src = wp;  dst = Wp_t;  N = 512;  k0 = ((t - 192) >> 3) * 64; n0 = ((t - 192) & 7) * 64; }

    __shared__ us T[64][72];
    #pragma unroll
    for (int i = 0; i < 4; ++i) {
        int s = tid + i * 256;
        int r = s >> 4, c4 = (s & 15) * 4;
        float4 v = *(const float4*)&src[(size_t)(k0 + r) * N + n0 + c4];
        T[r][c4 + 0] = f2bf(v.x); T[r][c4 + 1] = f2bf(v.y);
        T[r][c4 + 2] = f2bf(v.z); T[r][c4 + 3] = f2bf(v.w);
    }
    __syncthreads();
    #pragma unroll
    for (int i = 0; i < 2; ++i) {
        int s = tid + i * 256;
        int n = s >> 3, k8 = (s & 7) * 8;
        union { us u[8]; i32x4 v; } tmp;
        #pragma unroll
        for (int j = 0; j < 8; ++j) tmp.u[j] = T[k8 + j][n];
        *(i32x4*)&dst[(size_t)(n0 + n) * K + k0 + k8] = tmp.v;
    }
}

// ---------------------------------------------------------------------------
// 128x64-tile core (BK=64, 4 waves, wave = 64 rows x 32 cols).
// ---------------------------------------------------------------------------
__device__ __forceinline__ void core6432(const us* As, const us* Bs, int l, int w,
                                         f32x4 acc[4][2])
{
    const int wr = (w >> 1) * 64, wc = (w & 1) * 32;
    short8 af[4][2], bf_[2][2];
    #pragma unroll
    for (int rt = 0; rt < 4; ++rt) {
        int row = wr + rt * 16 + (l & 15);
        #pragma unroll
        for (int ks = 0; ks < 2; ++ks) {
            int slot = ks * 4 + (l >> 4);
            af[rt][ks] = *(const short8*)((const char*)As + row * 128 + ((slot ^ (row & 7)) * 16));
        }
    }
    #pragma unroll
    for (int ct = 0; ct < 2; ++ct) {
        int row = wc + ct * 16 + (l & 15);
        #pragma unroll
        for (int ks = 0; ks < 2; ++ks) {
            int slot = ks * 4 + (l >> 4);
            bf_[ct][ks] = *(const short8*)((const char*)Bs + row * 128 + ((slot ^ (row & 7)) * 16));
        }
    }
    #pragma unroll
    for (int ks = 0; ks < 2; ++ks)
        #pragma unroll
        for (int rt = 0; rt < 4; ++rt)
            #pragma unroll
            for (int ct = 0; ct < 2; ++ct)
                acc[rt][ct] = __builtin_amdgcn_mfma_f32_16x16x32_bf16(
                    af[rt][ks], bf_[ct][ks], acc[rt][ct], 0, 0, 0);
}

// ---------------------------------------------------------------------------
// Fused QKV GEMM, 128x64 tile, 2-phase double-buffered pipeline.
// z=0 Qh(*0.125), z=1 Kpack, z=2 Vpack.  grid (8, 32, 3).
// ---------------------------------------------------------------------------
__global__ __launch_bounds__(256, 2) void qkv128(
    const float* __restrict__ x_q, const float* __restrict__ x,
    const us* __restrict__ Wq_t, const us* __restrict__ Wkv_t,
    us* __restrict__ Qh, us* __restrict__ Kpack, us* __restrict__ Vpack)
{
    const int z = blockIdx.z;
    const float* Af = z ? x : x_q;
    const us* Bt    = z ? Wkv_t : Wq_t;
    const int m0 = blockIdx.y * 128, n0 = blockIdx.x * 64;
    const int bn0 = n0 + (z == 2 ? 512 : 0);
    const int hh = blockIdx.x;

    __shared__ us smem[24576];               // 48 KB: 2 x (As 8192 | Bs 4096)
    us* As0 = smem;          us* Bs0 = smem + 8192;
    us* As1 = smem + 12288;  us* Bs1 = smem + 20480;
    const int tid = threadIdx.x, l = tid & 63, w = tid >> 6;

    const us* gB = Bt + (size_t)(bn0 + w * 8 + (l >> 3)) * 512 + (size_t)(((l & 7) ^ (l >> 3)) * 8);
    const float* gA = Af + (size_t)(m0 + w * 32 + (l >> 4)) * 512 + (l & 15) * 4;

    float4 ar[8];
    f32x4 acc[4][2] = {};

    // prologue: stage tile 0
    #pragma unroll
    for (int i = 0; i < 2; ++i)
        __builtin_amdgcn_global_load_lds((gl_u32*)(gB + (size_t)i * 32 * 512),
                                         (lds_u32*)(Bs0 + (w * 8 + i * 32) * 64), 16, 0, 0);
    #pragma unroll
    for (int j = 0; j < 8; ++j) ar[j] = *(const float4*)(gA + (size_t)j * 4 * 512);
    #pragma unroll
    for (int j = 0; j < 8; ++j) {
        int row = w * 32 + j * 4 + (l >> 4);
        ull pk = (ull)f2bf(ar[j].x) | ((ull)f2bf(ar[j].y) << 16)
               | ((ull)f2bf(ar[j].z) << 32) | ((ull)f2bf(ar[j].w) << 48);
        int slot = (l & 15) >> 1, sub = l & 1;
        *(ull*)((char*)As0 + row * 128 + ((slot ^ (row & 7)) * 16) + sub * 8) = pk;
    }
    __syncthreads();

    for (int t = 0; t < 8; ++t) {
        us* Ascur = (t & 1) ? As1 : As0;
        us* Bscur = (t & 1) ? Bs1 : Bs0;
        us* Asnxt = (t & 1) ? As0 : As1;
        us* Bsnxt = (t & 1) ? Bs0 : Bs1;
        if (t < 7) {
            const int k1 = (t + 1) * 64;
            #pragma unroll
            for (int i = 0; i < 2; ++i)
                __builtin_amdgcn_global_load_lds((gl_u32*)(gB + (size_t)i * 32 * 512 + k1),
                                                 (lds_u32*)(Bsnxt + (w * 8 + i * 32) * 64), 16, 0, 0);
            #pragma unroll
            for (int j = 0; j < 8; ++j) ar[j] = *(const float4*)(gA + (size_t)j * 4 * 512 + k1);
        }
        core6432(Ascur, Bscur, l, w, acc);
        if (t < 7) {
            #pragma unroll
            for (int j = 0; j < 8; ++j) {
                int row = w * 32 + j * 4 + (l >> 4);
                ull pk = (ull)f2bf(ar[j].x) | ((ull)f2bf(ar[j].y) << 16)
                       | ((ull)f2bf(ar[j].z) << 32) | ((ull)f2bf(ar[j].w) << 48);
                int slot = (l & 15) >> 1, sub = l & 1;
                *(ull*)((char*)Asnxt + row * 128 + ((slot ^ (row & 7)) * 16) + sub * 8) = pk;
            }
        }
        __syncthreads();
    }

    const int wr = (w >> 1) * 64, wc = (w & 1) * 32;
    if (z == 0) {
        #pragma unroll
        for (int rt = 0; rt < 4; ++rt)
          #pragma unroll
          for (int ct = 0; ct < 2; ++ct)
            #pragma unroll
            for (int r = 0; r < 4; ++r) {
                int row = m0 + wr + rt * 16 + (l >> 4) * 4 + r;
                int d   = wc + ct * 16 + (l & 15);
                Qh[((size_t)((row >> 10) * H_ + hh) << 16) + (size_t)(row & 1023) * 64 + d]
                    = f2bf(acc[rt][ct][r] * 0.125f);
            }
    } else if (z == 1) {
        #pragma unroll
        for (int rt = 0; rt < 4; ++rt)
          #pragma unroll
          for (int ct = 0; ct < 2; ++ct)
            #pragma unroll
            for (int r = 0; r < 4; ++r) {
                int row = m0 + wr + rt * 16 + (l >> 4) * 4 + r;
                int d   = wc + ct * 16 + (l & 15);
                int bh = (row >> 10) * H_ + hh, tl = row & 1023;
                size_t byte = ((size_t)bh << 17) + (size_t)(tl >> 4) * 2048
                            + (size_t)(d >> 5) * 1024
                            + ((((d >> 3) & 3) * 16 + (tl & 15)) * 16) + (d & 7) * 2;
                *(us*)((char*)Kpack + byte) = f2bf(acc[rt][ct][r]);
            }
    } else {
        us* T = smem;                        // [128][68] = 17408 B
        #pragma unroll
        for (int rt = 0; rt < 4; ++rt)
          #pragma unroll
          for (int ct = 0; ct < 2; ++ct)
            #pragma unroll
            for (int r = 0; r < 4; ++r) {
                int rl = wr + rt * 16 + (l >> 4) * 4 + r;
                int cl = wc + ct * 16 + (l & 15);
                T[rl * 68 + cl] = f2bf(acc[rt][ct][r]);
            }
        __syncthreads();
        const int bb = m0 >> 10, tb = m0 & 1023;
        const int bh = bb * H_ + hh;
        #pragma unroll
        for (int i = 0; i < 4; ++i) {
            int s = tid + i * 256;
            int d = s & 63, kg = s >> 6;     // kg 0..15
            union { us u[8]; i32x4 v; } tmp;
            #pragma unroll
            for (int j = 0; j < 8; ++j) tmp.u[j] = T[(kg * 8 + j) * 68 + d];
            int key0 = tb + kg * 8;
            int kt = key0 >> 6, koff = key0 & 63;
            int p = koff >> 5, q4 = (koff >> 3) & 3;
            int dt = d >> 4, q = d & 15;
            size_t byte = ((size_t)bh << 17) + (size_t)((dt * 16 + kt) * 2 + p) * 1024
                        + (q4 * 16 + q) * 16;
            *(i32x4*)((char*)Vpack + byte) = tmp.v;
        }
    }
}

// ---------------------------------------------------------------------------
// out = Ob @ Wp_t^T + bias, 128x64 tile, 2-phase pipeline. grid (8, 32).
// ---------------------------------------------------------------------------
__global__ __launch_bounds__(256, 2) void out128(
    const us* __restrict__ Ob, const us* __restrict__ Wp_t,
    const float* __restrict__ bias, float* __restrict__ C)
{
    __shared__ us smem[24576];
    us* As0 = smem;          us* Bs0 = smem + 8192;
    us* As1 = smem + 12288;  us* Bs1 = smem + 20480;
    const int tid = threadIdx.x, l = tid & 63, w = tid >> 6;
    const int m0 = blockIdx.y * 128, n0 = blockIdx.x * 64;

    const us* gA = Ob   + (size_t)(m0 + w * 32 + (l >> 3)) * 512 + (size_t)(((l & 7) ^ (l >> 3)) * 8);
    const us* gB = Wp_t + (size_t)(n0 + w * 8  + (l >> 3)) * 512 + (size_t)(((l & 7) ^ (l >> 3)) * 8);

    f32x4 acc[4][2] = {};

    #pragma unroll
    for (int i = 0; i < 4; ++i)
        __builtin_amdgcn_global_load_lds((gl_u32*)(gA + (size_t)i * 8 * 512),
                                         (lds_u32*)(As0 + (w * 32 + i * 8) * 64), 16, 0, 0);
    #pragma unroll
    for (int i = 0; i < 2; ++i)
        __builtin_amdgcn_global_load_lds((gl_u32*)(gB + (size_t)i * 32 * 512),
                                         (lds_u32*)(Bs0 + (w * 8 + i * 32) * 64), 16, 0, 0);
    __syncthreads();

    for (int t = 0; t < 8; ++t) {
        us* Ascur = (t & 1) ? As1 : As0;
        us* Bscur = (t & 1) ? Bs1 : Bs0;
        us* Asnxt = (t & 1) ? As0 : As1;
        us* Bsnxt = (t & 1) ? Bs0 : Bs1;
        if (t < 7) {
            const int k1 = (t + 1) * 64;
            #pragma unroll
            for (int i = 0; i < 4; ++i)
                __builtin_amdgcn_global_load_lds((gl_u32*)(gA + (size_t)i * 8 * 512 + k1),
                                                 (lds_u32*)(Asnxt + (w * 32 + i * 8) * 64), 16, 0, 0);
            #pragma unroll
            for (int i = 0; i < 2; ++i)
                __builtin_amdgcn_global_load_lds((gl_u32*)(gB + (size_t)i * 32 * 512 + k1),
                                                 (lds_u32*)(Bsnxt + (w * 8 + i * 32) * 64), 16, 0, 0);
        }
        core6432(Ascur, Bscur, l, w, acc);
        __syncthreads();
    }

    const int wr = (w >> 1) * 64, wc = (w & 1) * 32;
    #pragma unroll
    for (int rt = 0; rt < 4; ++rt)
      #pragma unroll
      for (int ct = 0; ct < 2; ++ct)
        #pragma unroll
        for (int r = 0; r < 4; ++r) {
            int row = m0 + wr + rt * 16 + (l >> 4) * 4 + r;
            int col = n0 + wc + ct * 16 + (l & 15);
            __builtin_nontemporal_store(acc[rt][ct][r] + bias[col], &C[(size_t)row * 512 + col]);
        }
}

// ---------------------------------------------------------------------------
// Attention v6: 32 q-rows, 8 waves; XCD-grouped; fragment-native packed K/V;
// nt attn + Ob stores; V prefetch; setprio around all MFMA clusters.
// ---------------------------------------------------------------------------
__global__ __launch_bounds__(512, 4) void attn6(
    const us* __restrict__ Qhp, const us* __restrict__ Kpack, const us* __restrict__ Vpack,
    float* __restrict__ attnOut, us* __restrict__ Ob)
{
    const int tid = threadIdx.x, lane = tid & 63, w = tid >> 6;
    const int rg = w >> 2, wk = w & 3;
    const int p = blockIdx.x + 32 * blockIdx.y + 256 * blockIdx.z;
    const int g = (p & 7) + 8 * ((p >> 3) & 3);
    const int b = g >> 3, h = g & 7, q0 = (p >> 5) * 32;
    const int q = lane & 15, q4 = lane >> 4;
    const int bh = b * H_ + h;

    __shared__ us P[32 * 1024];              // 64 KB
    __shared__ float redM[2][4][16], redS[2][4][16];

    const us* qp = &Qhp[((size_t)bh << 16) + (size_t)(q0 + rg * 16 + q) * 64 + q4 * 8];
    short8 bq0 = *(const short8*)qp;
    short8 bq1 = *(const short8*)(qp + 32);

    const char* kb_base = (const char*)Kpack + ((size_t)bh << 17) + (size_t)wk * 16 * 2048 + lane * 16;

    f32x4 sv[16];
    #pragma unroll
    for (int ct = 0; ct < 16; ++ct) {
        const char* ka_ = kb_base + ct * 2048;
        short8 ka  = *(const short8*)ka_;
        short8 kb2 = *(const short8*)(ka_ + 1024);
        f32x4 a = {};
        __builtin_amdgcn_s_setprio(1);
        a = __builtin_amdgcn_mfma_f32_16x16x32_bf16(ka, bq0, a, 0, 0, 0);
        a = __builtin_amdgcn_mfma_f32_16x16x32_bf16(kb2, bq1, a, 0, 0, 0);
        __builtin_amdgcn_s_setprio(0);
        sv[ct] = a;
    }

    float m = sv[0][0];
    #pragma unroll
    for (int ct = 0; ct < 16; ++ct)
        #pragma unroll
        for (int r = 0; r < 4; ++r) m = fmaxf(m, sv[ct][r]);
    m = fmaxf(m, __shfl_xor(m, 16));
    m = fmaxf(m, __shfl_xor(m, 32));
    if (lane < 16) redM[rg][wk][lane] = m;
    __syncthreads();
    const float mg = fmaxf(fmaxf(redM[rg][0][q], redM[rg][1][q]),
                           fmaxf(redM[rg][2][q], redM[rg][3][q]));

    float s = 0.f;
    #pragma unroll
    for (int ct = 0; ct < 16; ++ct)
        #pragma unroll
        for (int r = 0; r < 4; ++r) {
            float e = __expf(sv[ct][r] - mg);
            sv[ct][r] = e;
            s += e;
        }
    s += __shfl_xor(s, 16);
    s += __shfl_xor(s, 32);
    if (lane < 16) redS[rg][wk][lane] = s;
    __syncthreads();
    const float inv = 1.0f / (redS[rg][0][q] + redS[rg][1][q] + redS[rg][2][q] + redS[rg][3][q]);

    const unsigned sw = (unsigned)(q & 7) << 4;
    #pragma unroll
    for (int ct = 0; ct < 16; ++ct) {
        const int key0 = wk * 256 + ct * 16 + q4 * 4;
        ull pk = (ull)f2bf(sv[ct][0] * inv)
               | ((ull)f2bf(sv[ct][1] * inv) << 16)
               | ((ull)f2bf(sv[ct][2] * inv) << 32)
               | ((ull)f2bf(sv[ct][3] * inv) << 48);
        unsigned byte = (unsigned)(rg * 16 + q) * 2048u + (((unsigned)(key0 * 2)) ^ sw);
        *(ull*)((char*)P + byte) = pk;
    }
    __syncthreads();

    // V prefetch (2 kt-steps) before the store phase
    const char* vbase = (const char*)Vpack + ((size_t)bh << 17)
                      + (size_t)wk * 32 * 1024 + lane * 16;
    short8 v0a = *(const short8*)(vbase);
    short8 v1a = *(const short8*)(vbase + 1024);

    // coalesced nt attn store: wave w stores block-rows w*4..w*4+3 (1KB/instr)
    {
        const size_t aRow = ((size_t)bh * NQ_ + q0) * NK_;
        #pragma unroll
        for (int i = 0; i < 4; ++i) {
            const int r = w * 4 + i;
            const unsigned swr = (unsigned)(r & 7) << 4;
            #pragma unroll
            for (int j = 0; j < 4; ++j) {
                unsigned byte = (unsigned)r * 2048u
                              + (((unsigned)(j * 512 + lane * 8)) ^ swr);
                ull pk = *(const ull*)((const char*)P + byte);
                f32x4 o;
                o[0] = __builtin_bit_cast(float, (unsigned)((pk & 0xFFFFull) << 16));
                o[1] = __builtin_bit_cast(float, (unsigned)(((pk >> 16) & 0xFFFFull) << 16));
                o[2] = __builtin_bit_cast(float, (unsigned)(((pk >> 32) & 0xFFFFull) << 16));
                o[3] = __builtin_bit_cast(float, (unsigned)((pk >> 48) << 16));
                __builtin_nontemporal_store(o,
                    (f32x4*)&attnOut[aRow + (size_t)r * NK_ + j * 256 + lane * 4]);
            }
        }
    }

    // PV
    f32x4 acc0 = {}, acc1 = {};
    const unsigned prow = (unsigned)(rg * 16 + q) * 2048u;
    #pragma unroll
    for (int kt = 0; kt < 16; ++kt) {
        short8 vb0 = v0a, vb1 = v1a;
        if (kt < 15) {
            v0a = *(const short8*)(vbase + (kt + 1) * 2048);
            v1a = *(const short8*)(vbase + (kt + 1) * 2048 + 1024);
        }
        const int kb = kt * 64;
        unsigned o0 = ((unsigned)((kb + q4 * 8) * 2)) ^ sw;
        unsigned o1 = ((unsigned)((kb + 32 + q4 * 8) * 2)) ^ sw;
        short8 pa0 = *(const short8*)((const char*)P + prow + o0);
        short8 pa1 = *(const short8*)((const char*)P + prow + o1);
        __builtin_amdgcn_s_setprio(1);
        acc0 = __builtin_amdgcn_mfma_f32_16x16x32_bf16(pa0, vb0, acc0, 0, 0, 0);
        acc1 = __builtin_amdgcn_mfma_f32_16x16x32_bf16(pa1, vb1, acc1, 0, 0, 0);
        __builtin_amdgcn_s_setprio(0);
    }
    #pragma unroll
    for (int r = 0; r < 4; ++r) {
        float o = acc0[r] + acc1[r];
        __builtin_nontemporal_store(f2bf(o),
            &Ob[(size_t)(b * NQ_ + q0 + rg * 16 + q4 * 4 + r) * 512 + h * 64 + wk * 16 + q]);
    }
}

// ---------------------------------------------------------------------------
extern "C" void kernel_launch(void* const* d_in, const int* in_sizes, int n_in,
                              void* d_out, int out_size, void* d_ws, size_t ws_size,
                              hipStream_t stream)
{
    (void)in_sizes; (void)n_in; (void)out_size; (void)ws_size;
    const float* x    = (const float*)d_in[0];
    const float* x_q  = (const float*)d_in[1];
    const float* w_q  = (const float*)d_in[2];
    const float* w_kv = (const float*)d_in[3];
    const float* w_p  = (const float*)d_in[4];
    const float* b_p  = (const float*)d_in[5];

    float* out   = (float*)d_out;
    float* attnO = out + (size_t)B_ * NQ_ * DM_;

    us* Wq_t  = (us*)d_ws;                  // 256K elems
    us* Wkv_t = Wq_t  + 262144;             // 512K
    us* Wp_t  = Wkv_t + 524288;             // 256K
    us* Qh    = Wp_t  + 262144;             // 2M
    us* Kp    = Qh    + 2097152;            // 2M
    us* Vp    = Kp    + 2097152;            // 2M
    us* Ob    = Vp    + 2097152;            // 2M  (~18.5 MB total)

    wprep<<<256, 256, 0, stream>>>(w_q, w_kv, w_p, Wq_t, Wkv_t, Wp_t);
    qkv128<<<dim3(8, 32, 3), 256, 0, stream>>>(x_q, x, Wq_t, Wkv_t, Qh, Kp, Vp);
    attn6<<<dim3(32, 8, 4), 512, 0, stream>>>(Qh, Kp, Vp, attnO, Ob);
    out128<<<dim3(8, 32), 256, 0, stream>>>(Ob, Wp_t, b_p, out);
}

// Round 8
// 85.508 us; speedup vs baseline: 1.0113x; 1.0113x over previous
//
#include <hip/hip_runtime.h>

#define B_   4
#define NQ_  1024
#define NK_  1024
#define H_   8
#define DM_  512

typedef unsigned short us;
typedef unsigned long long ull;
typedef __attribute__((ext_vector_type(8))) short  short8;
typedef __attribute__((ext_vector_type(4))) float  f32x4;
typedef __attribute__((ext_vector_type(4))) int    i32x4;
typedef __attribute__((address_space(3))) unsigned int       lds_u32;
typedef const __attribute__((address_space(1))) unsigned int gl_u32;

static __device__ __forceinline__ us f2bf(float f) {
    unsigned int u = __builtin_bit_cast(unsigned int, f);
    u += 0x7FFF + ((u >> 16) & 1);
    return (us)(u >> 16);
}

// ---------------------------------------------------------------------------
// wprep: weights f32[K][N] -> bf16 [N][K].  256 blocks.
// ---------------------------------------------------------------------------
__global__ __launch_bounds__(256) void wprep(
    const float* __restrict__ wq, const float* __restrict__ wkv,
    const float* __restrict__ wp,
    us* __restrict__ Wq_t, us* __restrict__ Wkv_t, us* __restrict__ Wp_t)
{
    const int t = blockIdx.x, tid = threadIdx.x;
    const float* src; us* dst; int k0, n0, N; const int K = 512;
    if (t < 64)       { src = wq;  dst = Wq_t;  N = 512;  k0 = (t >> 3) * 64;         n0 = (t & 7) * 64; }
    else if (t < 192) { src = wkv; dst = Wkv_t; N = 1024; k0 = ((t - 64) >> 4) * 64;  n0 = ((t - 64) & 15) * 64; }
    else              { src = wp;  dst = Wp_t;  N = 512;  k0 = ((t - 192) >> 3) * 64; n0 = ((t - 192) & 7) * 64; }

    __shared__ us T[64][72];
    #pragma unroll
    for (int i = 0; i < 4; ++i) {
        int s = tid + i * 256;
        int r = s >> 4, c4 = (s & 15) * 4;
        float4 v = *(const float4*)&src[(size_t)(k0 + r) * N + n0 + c4];
        T[r][c4 + 0] = f2bf(v.x); T[r][c4 + 1] = f2bf(v.y);
        T[r][c4 + 2] = f2bf(v.z); T[r][c4 + 3] = f2bf(v.w);
    }
    __syncthreads();
    #pragma unroll
    for (int i = 0; i < 2; ++i) {
        int s = tid + i * 256;
        int n = s >> 3, k8 = (s & 7) * 8;
        union { us u[8]; i32x4 v; } tmp;
        #pragma unroll
        for (int j = 0; j < 8; ++j) tmp.u[j] = T[k8 + j][n];
        *(i32x4*)&dst[(size_t)(n0 + n) * K + k0 + k8] = tmp.v;
    }
}

// ---------------------------------------------------------------------------
// 128x128 core (BK=64): reads As/Bs with XOR slot swizzle.
// ---------------------------------------------------------------------------
__device__ __forceinline__ void core128(const us* As, const us* Bs, int l, int w,
                                        f32x4 acc[4][4])
{
    const int wr = (w >> 1) * 64, wc = (w & 1) * 64;
    short8 af[4][2], bf_[4][2];
    #pragma unroll
    for (int rt = 0; rt < 4; ++rt) {
        int row = wr + rt * 16 + (l & 15);
        #pragma unroll
        for (int ks = 0; ks < 2; ++ks) {
            int slot = ks * 4 + (l >> 4);
            af[rt][ks] = *(const short8*)((const char*)As + row * 128 + ((slot ^ (row & 7)) * 16));
        }
    }
    #pragma unroll
    for (int ct = 0; ct < 4; ++ct) {
        int row = wc + ct * 16 + (l & 15);
        #pragma unroll
        for (int ks = 0; ks < 2; ++ks) {
            int slot = ks * 4 + (l >> 4);
            bf_[ct][ks] = *(const short8*)((const char*)Bs + row * 128 + ((slot ^ (row & 7)) * 16));
        }
    }
    #pragma unroll
    for (int ks = 0; ks < 2; ++ks)
        #pragma unroll
        for (int rt = 0; rt < 4; ++rt)
            #pragma unroll
            for (int ct = 0; ct < 4; ++ct)
                acc[rt][ct] = __builtin_amdgcn_mfma_f32_16x16x32_bf16(
                    af[rt][ks], bf_[ct][ks], acc[rt][ct], 0, 0, 0);
}

// ---------------------------------------------------------------------------
// Fused QKV GEMM: z=0 Qh(*0.125), z=1 Kpack, z=2 Vpack.  grid (4, 32, 3).
// ---------------------------------------------------------------------------
__global__ __launch_bounds__(256, 2) void qkv128(
    const float* __restrict__ x_q, const float* __restrict__ x,
    const us* __restrict__ Wq_t, const us* __restrict__ Wkv_t,
    us* __restrict__ Qh, us* __restrict__ Kpack, us* __restrict__ Vpack)
{
    const int z = blockIdx.z;
    const float* Af = z ? x : x_q;
    const us* Bt    = z ? Wkv_t : Wq_t;
    const int m0 = blockIdx.y * 128, n0 = blockIdx.x * 128;
    const int bn0 = n0 + (z == 2 ? 512 : 0);

    __shared__ us smem[16896];               // As 16KB | Bs 16KB ; T reuses all
    us* As = smem; us* Bs = smem + 8192;
    const int tid = threadIdx.x, l = tid & 63, w = tid >> 6;

    const int rr0 = w * 32 + (l >> 3);
    const int ss  = (l & 7) ^ ((l >> 3) & 7);
    const us* gB = Bt + (size_t)(bn0 + rr0) * 512 + ss * 8;
    const float* gA = Af + (size_t)(m0 + w * 32 + (l >> 4)) * 512 + (l & 15) * 4;

    f32x4 acc[4][4] = {};
    for (int k0 = 0; k0 < 512; k0 += 64) {
        #pragma unroll
        for (int i = 0; i < 4; ++i)
            __builtin_amdgcn_global_load_lds((gl_u32*)(gB + (size_t)i * 8 * 512 + k0),
                                             (lds_u32*)(Bs + (w * 32 + i * 8) * 64), 16, 0, 0);
        #pragma unroll
        for (int j = 0; j < 8; ++j) {
            float4 f = *(const float4*)(gA + (size_t)j * 4 * 512 + k0);
            int row = w * 32 + j * 4 + (l >> 4);
            ull pk = (ull)f2bf(f.x) | ((ull)f2bf(f.y) << 16)
                   | ((ull)f2bf(f.z) << 32) | ((ull)f2bf(f.w) << 48);
            int slot = (l & 15) >> 1, sub = l & 1;
            *(ull*)((char*)As + row * 128 + ((slot ^ (row & 7)) * 16) + sub * 8) = pk;
        }
        __syncthreads();
        core128(As, Bs, l, w, acc);
        __syncthreads();
    }

    const int wr = (w >> 1) * 64, wc = (w & 1) * 64;
    if (z == 0) {
        #pragma unroll
        for (int rt = 0; rt < 4; ++rt)
          #pragma unroll
          for (int ct = 0; ct < 4; ++ct)
            #pragma unroll
            for (int r = 0; r < 4; ++r) {
                int row = m0 + wr + rt * 16 + (l >> 4) * 4 + r;
                int col = n0 + wc + ct * 16 + (l & 15);
                int hh = col >> 6, d = col & 63;
                Qh[((size_t)((row >> 10) * H_ + hh) << 16) + (size_t)(row & 1023) * 64 + d]
                    = f2bf(acc[rt][ct][r] * 0.125f);
            }
    } else if (z == 1) {
        #pragma unroll
        for (int rt = 0; rt < 4; ++rt)
          #pragma unroll
          for (int ct = 0; ct < 4; ++ct)
            #pragma unroll
            for (int r = 0; r < 4; ++r) {
                int row = m0 + wr + rt * 16 + (l >> 4) * 4 + r;
                int col = n0 + wc + ct * 16 + (l & 15);
                int hh = col >> 6, d = col & 63;
                int bh = (row >> 10) * H_ + hh, tl = row & 1023;
                size_t byte = ((size_t)bh << 17) + (size_t)(tl >> 4) * 2048
                            + (size_t)(d >> 5) * 1024
                            + ((((d >> 3) & 3) * 16 + (tl & 15)) * 16) + (d & 7) * 2;
                *(us*)((char*)Kpack + byte) = f2bf(acc[rt][ct][r]);
            }
    } else {
        us* T = smem;                        // [128][132]
        #pragma unroll
        for (int rt = 0; rt < 4; ++rt)
          #pragma unroll
          for (int ct = 0; ct < 4; ++ct)
            #pragma unroll
            for (int r = 0; r < 4; ++r) {
                int rl = wr + rt * 16 + (l >> 4) * 4 + r;
                int cl = wc + ct * 16 + (l & 15);
                T[rl * 132 + cl] = f2bf(acc[rt][ct][r]);
            }
        __syncthreads();
        const int bb = m0 >> 10, tb = m0 & 1023;
        #pragma unroll
        for (int i = 0; i < 8; ++i) {
            int s = tid + i * 256;
            int col = s >> 4, r8 = (s & 15) * 8;
            union { us u[8]; i32x4 v; } tmp;
            #pragma unroll
            for (int j = 0; j < 8; ++j) tmp.u[j] = T[(r8 + j) * 132 + col];
            int gcol = n0 + col;
            int hh = gcol >> 6, d = gcol & 63;
            int bh = bb * H_ + hh;
            int tl0 = tb + r8;
            int dt = d >> 4, q = d & 15;
            int kt = tl0 >> 6, koff = tl0 & 63;
            int p = koff >> 5, q4 = (koff >> 3) & 3;
            size_t byte = ((size_t)bh << 17) + (size_t)((dt * 16 + kt) * 2 + p) * 1024
                        + (q4 * 16 + q) * 16;
            *(i32x4*)((char*)Vpack + byte) = tmp.v;
        }
    }
}

// ---------------------------------------------------------------------------
// out = Ob @ Wp_t^T + bias  (A bf16 global_load_lds, nt fp32 stores)
// ---------------------------------------------------------------------------
__global__ __launch_bounds__(256, 2) void out128(
    const us* __restrict__ Ob, const us* __restrict__ Wp_t,
    const float* __restrict__ bias, float* __restrict__ C)
{
    __shared__ us As[128 * 64], Bs[128 * 64];
    const int tid = threadIdx.x, l = tid & 63, w = tid >> 6;
    const int m0 = blockIdx.y * 128, n0 = blockIdx.x * 128;

    const int rr0 = w * 32 + (l >> 3);
    const int ss  = (l & 7) ^ ((l >> 3) & 7);
    const us* gA = Ob   + (size_t)(m0 + rr0) * 512 + ss * 8;
    const us* gB = Wp_t + (size_t)(n0 + rr0) * 512 + ss * 8;

    f32x4 acc[4][4] = {};
    for (int k0 = 0; k0 < 512; k0 += 64) {
        #pragma unroll
        for (int i = 0; i < 4; ++i) {
            __builtin_amdgcn_global_load_lds((gl_u32*)(gA + (size_t)i * 8 * 512 + k0),
                                             (lds_u32*)(As + (w * 32 + i * 8) * 64), 16, 0, 0);
            __builtin_amdgcn_global_load_lds((gl_u32*)(gB + (size_t)i * 8 * 512 + k0),
                                             (lds_u32*)(Bs + (w * 32 + i * 8) * 64), 16, 0, 0);
        }
        __syncthreads();
        core128(As, Bs, l, w, acc);
        __syncthreads();
    }

    const int wr = (w >> 1) * 64, wc = (w & 1) * 64;
    #pragma unroll
    for (int rt = 0; rt < 4; ++rt)
      #pragma unroll
      for (int ct = 0; ct < 4; ++ct)
        #pragma unroll
        for (int r = 0; r < 4; ++r) {
            int row = m0 + wr + rt * 16 + (l >> 4) * 4 + r;
            int col = n0 + wc + ct * 16 + (l & 15);
            __builtin_nontemporal_store(acc[rt][ct][r] + bias[col], &C[(size_t)row * 512 + col]);
        }
}

// ---------------------------------------------------------------------------
// Attention v7: round-5 structure (32 q-rows, 8 waves, XCD-grouped,
// fragment-native K/V) with the attn-store phase MERGED into the PV loop:
// each kt does {V prefetch, one 1KB nt store chunk, 2 PV MFMAs} so the
// 128MB write stream drains under MFMA issue.
// ---------------------------------------------------------------------------
__global__ __launch_bounds__(512, 4) void attn7(
    const us* __restrict__ Qhp, const us* __restrict__ Kpack, const us* __restrict__ Vpack,
    float* __restrict__ attnOut, us* __restrict__ Ob)
{
    const int tid = threadIdx.x, lane = tid & 63, w = tid >> 6;
    const int rg = w >> 2, wk = w & 3;
    const int p = blockIdx.x + 32 * blockIdx.y + 256 * blockIdx.z;
    const int g = (p & 7) + 8 * ((p >> 3) & 3);
    const int b = g >> 3, h = g & 7, q0 = (p >> 5) * 32;
    const int q = lane & 15, q4 = lane >> 4;
    const int bh = b * H_ + h;

    __shared__ us P[32 * 1024];              // 64 KB
    __shared__ float redM[2][4][16], redS[2][4][16];

    const us* qp = &Qhp[((size_t)bh << 16) + (size_t)(q0 + rg * 16 + q) * 64 + q4 * 8];
    short8 bq0 = *(const short8*)qp;
    short8 bq1 = *(const short8*)(qp + 32);

    const char* kb_base = (const char*)Kpack + ((size_t)bh << 17) + (size_t)wk * 16 * 2048 + lane * 16;

    f32x4 sv[16];
    #pragma unroll
    for (int ct = 0; ct < 16; ++ct) {
        const char* ka_ = kb_base + ct * 2048;
        short8 ka  = *(const short8*)ka_;
        short8 kb2 = *(const short8*)(ka_ + 1024);
        f32x4 a = {};
        a = __builtin_amdgcn_mfma_f32_16x16x32_bf16(ka, bq0, a, 0, 0, 0);
        a = __builtin_amdgcn_mfma_f32_16x16x32_bf16(kb2, bq1, a, 0, 0, 0);
        sv[ct] = a;
    }

    float m = sv[0][0];
    #pragma unroll
    for (int ct = 0; ct < 16; ++ct)
        #pragma unroll
        for (int r = 0; r < 4; ++r) m = fmaxf(m, sv[ct][r]);
    m = fmaxf(m, __shfl_xor(m, 16));
    m = fmaxf(m, __shfl_xor(m, 32));
    if (lane < 16) redM[rg][wk][lane] = m;
    __syncthreads();
    const float mg = fmaxf(fmaxf(redM[rg][0][q], redM[rg][1][q]),
                           fmaxf(redM[rg][2][q], redM[rg][3][q]));

    float s = 0.f;
    #pragma unroll
    for (int ct = 0; ct < 16; ++ct)
        #pragma unroll
        for (int r = 0; r < 4; ++r) {
            float e = __expf(sv[ct][r] - mg);
            sv[ct][r] = e;
            s += e;
        }
    s += __shfl_xor(s, 16);
    s += __shfl_xor(s, 32);
    if (lane < 16) redS[rg][wk][lane] = s;
    __syncthreads();
    const float inv = 1.0f / (redS[rg][0][q] + redS[rg][1][q] + redS[rg][2][q] + redS[rg][3][q]);

    const unsigned sw = (unsigned)(q & 7) << 4;
    #pragma unroll
    for (int ct = 0; ct < 16; ++ct) {
        const int key0 = wk * 256 + ct * 16 + q4 * 4;
        ull pk = (ull)f2bf(sv[ct][0] * inv)
               | ((ull)f2bf(sv[ct][1] * inv) << 16)
               | ((ull)f2bf(sv[ct][2] * inv) << 32)
               | ((ull)f2bf(sv[ct][3] * inv) << 48);
        unsigned byte = (unsigned)(rg * 16 + q) * 2048u + (((unsigned)(key0 * 2)) ^ sw);
        *(ull*)((char*)P + byte) = pk;
    }
    __syncthreads();

    // V prefetch (2 kt-steps)
    const char* vbase = (const char*)Vpack + ((size_t)bh << 17)
                      + (size_t)wk * 32 * 1024 + lane * 16;
    short8 v0a = *(const short8*)(vbase);
    short8 v1a = *(const short8*)(vbase + 1024);

    // merged attn-store + PV loop: 16 iterations, one 1KB store chunk + 2 MFMAs
    f32x4 acc0 = {}, acc1 = {};
    const unsigned prow = (unsigned)(rg * 16 + q) * 2048u;
    const size_t aRow = ((size_t)bh * NQ_ + q0) * NK_;
    #pragma unroll
    for (int kt = 0; kt < 16; ++kt) {
        short8 vb0 = v0a, vb1 = v1a;
        if (kt < 15) {
            v0a = *(const short8*)(vbase + (kt + 1) * 2048);
            v1a = *(const short8*)(vbase + (kt + 1) * 2048 + 1024);
        }
        // attn-store chunk: row r = w*4 + (kt>>2), col chunk j = kt&3
        {
            const int r = w * 4 + (kt >> 2);
            const int j = kt & 3;
            const unsigned swr = (unsigned)(r & 7) << 4;
            unsigned byte = (unsigned)r * 2048u
                          + (((unsigned)(j * 512 + lane * 8)) ^ swr);
            ull pk = *(const ull*)((const char*)P + byte);
            f32x4 o;
            o[0] = __builtin_bit_cast(float, (unsigned)((pk & 0xFFFFull) << 16));
            o[1] = __builtin_bit_cast(float, (unsigned)(((pk >> 16) & 0xFFFFull) << 16));
            o[2] = __builtin_bit_cast(float, (unsigned)(((pk >> 32) & 0xFFFFull) << 16));
            o[3] = __builtin_bit_cast(float, (unsigned)((pk >> 48) << 16));
            __builtin_nontemporal_store(o,
                (f32x4*)&attnOut[aRow + (size_t)r * NK_ + j * 256 + lane * 4]);
        }
        const int kb = kt * 64;
        unsigned o0 = ((unsigned)((kb + q4 * 8) * 2)) ^ sw;
        unsigned o1 = ((unsigned)((kb + 32 + q4 * 8) * 2)) ^ sw;
        short8 pa0 = *(const short8*)((const char*)P + prow + o0);
        short8 pa1 = *(const short8*)((const char*)P + prow + o1);
        __builtin_amdgcn_s_setprio(1);
        acc0 = __builtin_amdgcn_mfma_f32_16x16x32_bf16(pa0, vb0, acc0, 0, 0, 0);
        acc1 = __builtin_amdgcn_mfma_f32_16x16x32_bf16(pa1, vb1, acc1, 0, 0, 0);
        __builtin_amdgcn_s_setprio(0);
    }
    #pragma unroll
    for (int r = 0; r < 4; ++r) {
        float o = acc0[r] + acc1[r];
        Ob[(size_t)(b * NQ_ + q0 + rg * 16 + q4 * 4 + r) * 512 + h * 64 + wk * 16 + q] = f2bf(o);
    }
}

// ---------------------------------------------------------------------------
extern "C" void kernel_launch(void* const* d_in, const int* in_sizes, int n_in,
                              void* d_out, int out_size, void* d_ws, size_t ws_size,
                              hipStream_t stream)
{
    (void)in_sizes; (void)n_in; (void)out_size; (void)ws_size;
    const float* x    = (const float*)d_in[0];
    const float* x_q  = (const float*)d_in[1];
    const float* w_q  = (const float*)d_in[2];
    const float* w_kv = (const float*)d_in[3];
    const float* w_p  = (const float*)d_in[4];
    const float* b_p  = (const float*)d_in[5];

    float* out   = (float*)d_out;
    float* attnO = out + (size_t)B_ * NQ_ * DM_;

    us* Wq_t  = (us*)d_ws;                  // 256K elems
    us* Wkv_t = Wq_t  + 262144;             // 512K
    us* Wp_t  = Wkv_t + 524288;             // 256K
    us* Qh    = Wp_t  + 262144;             // 2M
    us* Kp    = Qh    + 2097152;            // 2M
    us* Vp    = Kp    + 2097152;            // 2M
    us* Ob    = Vp    + 2097152;            // 2M  (~18.5 MB total)

    wprep<<<256, 256, 0, stream>>>(w_q, w_kv, w_p, Wq_t, Wkv_t, Wp_t);
    qkv128<<<dim3(4, 32, 3), 256, 0, stream>>>(x_q, x, Wq_t, Wkv_t, Qh, Kp, Vp);
    attn7<<<dim3(32, 8, 4), 512, 0, stream>>>(Qh, Kp, Vp, attnO, Ob);
    out128<<<dim3(4, 32), 256, 0, stream>>>(Ob, Wp_t, b_p, out);
}

// Round 9
// 82.884 us; speedup vs baseline: 1.0433x; 1.0317x over previous
//
#include <hip/hip_runtime.h>

#define B_   4
#define NQ_  1024
#define NK_  1024
#define H_   8
#define DM_  512

typedef unsigned short us;
typedef unsigned long long ull;
typedef __attribute__((ext_vector_type(8))) short  short8;
typedef __attribute__((ext_vector_type(4))) float  f32x4;
typedef __attribute__((ext_vector_type(4))) int    i32x4;
typedef __attribute__((address_space(3))) unsigned int       lds_u32;
typedef const __attribute__((address_space(1))) unsigned int gl_u32;

static __device__ __forceinline__ us f2bf(float f) {
    unsigned int u = __builtin_bit_cast(unsigned int, f);
    u += 0x7FFF + ((u >> 16) & 1);
    return (us)(u >> 16);
}

// ---------------------------------------------------------------------------
// wprep: weights f32[K][N] -> bf16 [N][K].  256 blocks.
// ---------------------------------------------------------------------------
__global__ __launch_bounds__(256) void wprep(
    const float* __restrict__ wq, const float* __restrict__ wkv,
    const float* __restrict__ wp,
    us* __restrict__ Wq_t, us* __restrict__ Wkv_t, us* __restrict__ Wp_t)
{
    const int t = blockIdx.x, tid = threadIdx.x;
    const float* src; us* dst; int k0, n0, N; const int K = 512;
    if (t < 64)       { src = wq;  dst = Wq_t;  N = 512;  k0 = (t >> 3) * 64;         n0 = (t & 7) * 64; }
    else if (t < 192) { src = wkv; dst = Wkv_t; N = 1024; k0 = ((t - 64) >> 4) * 64;  n0 = ((t - 64) & 15) * 64; }
    else              { src = wp;  dst = Wp_t;  N = 512;  k0 = ((t - 192) >> 3) * 64; n0 = ((t - 192) & 7) * 64; }

    __shared__ us T[64][72];
    #pragma unroll
    for (int i = 0; i < 4; ++i) {
        int s = tid + i * 256;
        int r = s >> 4, c4 = (s & 15) * 4;
        float4 v = *(const float4*)&src[(size_t)(k0 + r) * N + n0 + c4];
        T[r][c4 + 0] = f2bf(v.x); T[r][c4 + 1] = f2bf(v.y);
        T[r][c4 + 2] = f2bf(v.z); T[r][c4 + 3] = f2bf(v.w);
    }
    __syncthreads();
    #pragma unroll
    for (int i = 0; i < 2; ++i) {
        int s = tid + i * 256;
        int n = s >> 3, k8 = (s & 7) * 8;
        union { us u[8]; i32x4 v; } tmp;
        #pragma unroll
        for (int j = 0; j < 8; ++j) tmp.u[j] = T[k8 + j][n];
        *(i32x4*)&dst[(size_t)(n0 + n) * K + k0 + k8] = tmp.v;
    }
}

// ---------------------------------------------------------------------------
// 128x128 core (BK=64): reads As/Bs with XOR slot swizzle.
// ---------------------------------------------------------------------------
__device__ __forceinline__ void core128(const us* As, const us* Bs, int l, int w,
                                        f32x4 acc[4][4])
{
    const int wr = (w >> 1) * 64, wc = (w & 1) * 64;
    short8 af[4][2], bf_[4][2];
    #pragma unroll
    for (int rt = 0; rt < 4; ++rt) {
        int row = wr + rt * 16 + (l & 15);
        #pragma unroll
        for (int ks = 0; ks < 2; ++ks) {
            int slot = ks * 4 + (l >> 4);
            af[rt][ks] = *(const short8*)((const char*)As + row * 128 + ((slot ^ (row & 7)) * 16));
        }
    }
    #pragma unroll
    for (int ct = 0; ct < 4; ++ct) {
        int row = wc + ct * 16 + (l & 15);
        #pragma unroll
        for (int ks = 0; ks < 2; ++ks) {
            int slot = ks * 4 + (l >> 4);
            bf_[ct][ks] = *(const short8*)((const char*)Bs + row * 128 + ((slot ^ (row & 7)) * 16));
        }
    }
    #pragma unroll
    for (int ks = 0; ks < 2; ++ks)
        #pragma unroll
        for (int rt = 0; rt < 4; ++rt)
            #pragma unroll
            for (int ct = 0; ct < 4; ++ct)
                acc[rt][ct] = __builtin_amdgcn_mfma_f32_16x16x32_bf16(
                    af[rt][ks], bf_[ct][ks], acc[rt][ct], 0, 0, 0);
}

// ---------------------------------------------------------------------------
// 128x64-tile core (BK=64, 4 waves, wave = 64 rows x 32 cols).
// ---------------------------------------------------------------------------
__device__ __forceinline__ void core6432(const us* As, const us* Bs, int l, int w,
                                         f32x4 acc[4][2])
{
    const int wr = (w >> 1) * 64, wc = (w & 1) * 32;
    short8 af[4][2], bf_[2][2];
    #pragma unroll
    for (int rt = 0; rt < 4; ++rt) {
        int row = wr + rt * 16 + (l & 15);
        #pragma unroll
        for (int ks = 0; ks < 2; ++ks) {
            int slot = ks * 4 + (l >> 4);
            af[rt][ks] = *(const short8*)((const char*)As + row * 128 + ((slot ^ (row & 7)) * 16));
        }
    }
    #pragma unroll
    for (int ct = 0; ct < 2; ++ct) {
        int row = wc + ct * 16 + (l & 15);
        #pragma unroll
        for (int ks = 0; ks < 2; ++ks) {
            int slot = ks * 4 + (l >> 4);
            bf_[ct][ks] = *(const short8*)((const char*)Bs + row * 128 + ((slot ^ (row & 7)) * 16));
        }
    }
    #pragma unroll
    for (int ks = 0; ks < 2; ++ks)
        #pragma unroll
        for (int rt = 0; rt < 4; ++rt)
            #pragma unroll
            for (int ct = 0; ct < 2; ++ct)
                acc[rt][ct] = __builtin_amdgcn_mfma_f32_16x16x32_bf16(
                    af[rt][ks], bf_[ct][ks], acc[rt][ct], 0, 0, 0);
}

// ---------------------------------------------------------------------------
// Fused QKV GEMM: z=0 Qh(*0.125), z=1 Kpack, z=2 Vpack.  grid (4, 32, 3).
// ---------------------------------------------------------------------------
__global__ __launch_bounds__(256, 2) void qkv128(
    const float* __restrict__ x_q, const float* __restrict__ x,
    const us* __restrict__ Wq_t, const us* __restrict__ Wkv_t,
    us* __restrict__ Qh, us* __restrict__ Kpack, us* __restrict__ Vpack)
{
    const int z = blockIdx.z;
    const float* Af = z ? x : x_q;
    const us* Bt    = z ? Wkv_t : Wq_t;
    const int m0 = blockIdx.y * 128, n0 = blockIdx.x * 128;
    const int bn0 = n0 + (z == 2 ? 512 : 0);

    __shared__ us smem[16896];               // As 16KB | Bs 16KB ; T reuses all
    us* As = smem; us* Bs = smem + 8192;
    const int tid = threadIdx.x, l = tid & 63, w = tid >> 6;

    const int rr0 = w * 32 + (l >> 3);
    const int ss  = (l & 7) ^ ((l >> 3) & 7);
    const us* gB = Bt + (size_t)(bn0 + rr0) * 512 + ss * 8;
    const float* gA = Af + (size_t)(m0 + w * 32 + (l >> 4)) * 512 + (l & 15) * 4;

    f32x4 acc[4][4] = {};
    for (int k0 = 0; k0 < 512; k0 += 64) {
        #pragma unroll
        for (int i = 0; i < 4; ++i)
            __builtin_amdgcn_global_load_lds((gl_u32*)(gB + (size_t)i * 8 * 512 + k0),
                                             (lds_u32*)(Bs + (w * 32 + i * 8) * 64), 16, 0, 0);
        #pragma unroll
        for (int j = 0; j < 8; ++j) {
            float4 f = *(const float4*)(gA + (size_t)j * 4 * 512 + k0);
            int row = w * 32 + j * 4 + (l >> 4);
            ull pk = (ull)f2bf(f.x) | ((ull)f2bf(f.y) << 16)
                   | ((ull)f2bf(f.z) << 32) | ((ull)f2bf(f.w) << 48);
            int slot = (l & 15) >> 1, sub = l & 1;
            *(ull*)((char*)As + row * 128 + ((slot ^ (row & 7)) * 16) + sub * 8) = pk;
        }
        __syncthreads();
        core128(As, Bs, l, w, acc);
        __syncthreads();
    }

    const int wr = (w >> 1) * 64, wc = (w & 1) * 64;
    if (z == 0) {
        #pragma unroll
        for (int rt = 0; rt < 4; ++rt)
          #pragma unroll
          for (int ct = 0; ct < 4; ++ct)
            #pragma unroll
            for (int r = 0; r < 4; ++r) {
                int row = m0 + wr + rt * 16 + (l >> 4) * 4 + r;
                int col = n0 + wc + ct * 16 + (l & 15);
                int hh = col >> 6, d = col & 63;
                Qh[((size_t)((row >> 10) * H_ + hh) << 16) + (size_t)(row & 1023) * 64 + d]
                    = f2bf(acc[rt][ct][r] * 0.125f);
            }
    } else if (z == 1) {
        #pragma unroll
        for (int rt = 0; rt < 4; ++rt)
          #pragma unroll
          for (int ct = 0; ct < 4; ++ct)
            #pragma unroll
            for (int r = 0; r < 4; ++r) {
                int row = m0 + wr + rt * 16 + (l >> 4) * 4 + r;
                int col = n0 + wc + ct * 16 + (l & 15);
                int hh = col >> 6, d = col & 63;
                int bh = (row >> 10) * H_ + hh, tl = row & 1023;
                size_t byte = ((size_t)bh << 17) + (size_t)(tl >> 4) * 2048
                            + (size_t)(d >> 5) * 1024
                            + ((((d >> 3) & 3) * 16 + (tl & 15)) * 16) + (d & 7) * 2;
                *(us*)((char*)Kpack + byte) = f2bf(acc[rt][ct][r]);
            }
    } else {
        us* T = smem;                        // [128][132]
        #pragma unroll
        for (int rt = 0; rt < 4; ++rt)
          #pragma unroll
          for (int ct = 0; ct < 4; ++ct)
            #pragma unroll
            for (int r = 0; r < 4; ++r) {
                int rl = wr + rt * 16 + (l >> 4) * 4 + r;
                int cl = wc + ct * 16 + (l & 15);
                T[rl * 132 + cl] = f2bf(acc[rt][ct][r]);
            }
        __syncthreads();
        const int bb = m0 >> 10, tb = m0 & 1023;
        #pragma unroll
        for (int i = 0; i < 8; ++i) {
            int s = tid + i * 256;
            int col = s >> 4, r8 = (s & 15) * 8;
            union { us u[8]; i32x4 v; } tmp;
            #pragma unroll
            for (int j = 0; j < 8; ++j) tmp.u[j] = T[(r8 + j) * 132 + col];
            int gcol = n0 + col;
            int hh = gcol >> 6, d = gcol & 63;
            int bh = bb * H_ + hh;
            int tl0 = tb + r8;
            int dt = d >> 4, q = d & 15;
            int kt = tl0 >> 6, koff = tl0 & 63;
            int p = koff >> 5, q4 = (koff >> 3) & 3;
            size_t byte = ((size_t)bh << 17) + (size_t)((dt * 16 + kt) * 2 + p) * 1024
                        + (q4 * 16 + q) * 16;
            *(i32x4*)((char*)Vpack + byte) = tmp.v;
        }
    }
}

// ---------------------------------------------------------------------------
// out = Ob @ Wp_t^T + bias.  128x64 tile -> 256 blocks (full CU coverage).
// ---------------------------------------------------------------------------
__global__ __launch_bounds__(256, 2) void out128(
    const us* __restrict__ Ob, const us* __restrict__ Wp_t,
    const float* __restrict__ bias, float* __restrict__ C)
{
    __shared__ us As[128 * 64], Bs[64 * 64];
    const int tid = threadIdx.x, l = tid & 63, w = tid >> 6;
    const int m0 = blockIdx.y * 128, n0 = blockIdx.x * 64;

    const us* gA = Ob   + (size_t)(m0 + w * 32 + (l >> 3)) * 512 + (size_t)(((l & 7) ^ (l >> 3)) * 8);
    const us* gB = Wp_t + (size_t)(n0 + w * 8  + (l >> 3)) * 512 + (size_t)(((l & 7) ^ (l >> 3)) * 8);

    f32x4 acc[4][2] = {};
    for (int k0 = 0; k0 < 512; k0 += 64) {
        #pragma unroll
        for (int i = 0; i < 4; ++i)
            __builtin_amdgcn_global_load_lds((gl_u32*)(gA + (size_t)i * 8 * 512 + k0),
                                             (lds_u32*)(As + (w * 32 + i * 8) * 64), 16, 0, 0);
        #pragma unroll
        for (int i = 0; i < 2; ++i)
            __builtin_amdgcn_global_load_lds((gl_u32*)(gB + (size_t)i * 32 * 512 + k0),
                                             (lds_u32*)(Bs + (w * 8 + i * 32) * 64), 16, 0, 0);
        __syncthreads();
        core6432(As, Bs, l, w, acc);
        __syncthreads();
    }

    const int wr = (w >> 1) * 64, wc = (w & 1) * 32;
    #pragma unroll
    for (int rt = 0; rt < 4; ++rt)
      #pragma unroll
      for (int ct = 0; ct < 2; ++ct)
        #pragma unroll
        for (int r = 0; r < 4; ++r) {
            int row = m0 + wr + rt * 16 + (l >> 4) * 4 + r;
            int col = n0 + wc + ct * 16 + (l & 15);
            C[(size_t)row * 512 + col] = acc[rt][ct][r] + bias[col];
        }
}

// ---------------------------------------------------------------------------
// Attention v5 (round-5 exact): 32 q-rows, 8 waves; XCD-grouped blocks;
// fragment-native Kpack/Vpack 1KB-coalesced loads; nt attn stores;
// V prefetch; setprio PV.
// ---------------------------------------------------------------------------
__global__ __launch_bounds__(512, 4) void attn5(
    const us* __restrict__ Qhp, const us* __restrict__ Kpack, const us* __restrict__ Vpack,
    float* __restrict__ attnOut, us* __restrict__ Ob)
{
    const int tid = threadIdx.x, lane = tid & 63, w = tid >> 6;
    const int rg = w >> 2, wk = w & 3;
    const int p = blockIdx.x + 32 * blockIdx.y + 256 * blockIdx.z;
    const int g = (p & 7) + 8 * ((p >> 3) & 3);
    const int b = g >> 3, h = g & 7, q0 = (p >> 5) * 32;
    const int q = lane & 15, q4 = lane >> 4;
    const int bh = b * H_ + h;

    __shared__ us P[32 * 1024];              // 64 KB
    __shared__ float redM[2][4][16], redS[2][4][16];

    const us* qp = &Qhp[((size_t)bh << 16) + (size_t)(q0 + rg * 16 + q) * 64 + q4 * 8];
    short8 bq0 = *(const short8*)qp;
    short8 bq1 = *(const short8*)(qp + 32);

    const char* kb_base = (const char*)Kpack + ((size_t)bh << 17) + (size_t)wk * 16 * 2048 + lane * 16;

    f32x4 sv[16];
    #pragma unroll
    for (int ct = 0; ct < 16; ++ct) {
        const char* ka_ = kb_base + ct * 2048;
        short8 ka  = *(const short8*)ka_;
        short8 kb2 = *(const short8*)(ka_ + 1024);
        f32x4 a = {};
        a = __builtin_amdgcn_mfma_f32_16x16x32_bf16(ka, bq0, a, 0, 0, 0);
        a = __builtin_amdgcn_mfma_f32_16x16x32_bf16(kb2, bq1, a, 0, 0, 0);
        sv[ct] = a;
    }

    float m = sv[0][0];
    #pragma unroll
    for (int ct = 0; ct < 16; ++ct)
        #pragma unroll
        for (int r = 0; r < 4; ++r) m = fmaxf(m, sv[ct][r]);
    m = fmaxf(m, __shfl_xor(m, 16));
    m = fmaxf(m, __shfl_xor(m, 32));
    if (lane < 16) redM[rg][wk][lane] = m;
    __syncthreads();
    const float mg = fmaxf(fmaxf(redM[rg][0][q], redM[rg][1][q]),
                           fmaxf(redM[rg][2][q], redM[rg][3][q]));

    float s = 0.f;
    #pragma unroll
    for (int ct = 0; ct < 16; ++ct)
        #pragma unroll
        for (int r = 0; r < 4; ++r) {
            float e = __expf(sv[ct][r] - mg);
            sv[ct][r] = e;
            s += e;
        }
    s += __shfl_xor(s, 16);
    s += __shfl_xor(s, 32);
    if (lane < 16) redS[rg][wk][lane] = s;
    __syncthreads();
    const float inv = 1.0f / (redS[rg][0][q] + redS[rg][1][q] + redS[rg][2][q] + redS[rg][3][q]);

    const unsigned sw = (unsigned)(q & 7) << 4;
    #pragma unroll
    for (int ct = 0; ct < 16; ++ct) {
        const int key0 = wk * 256 + ct * 16 + q4 * 4;
        ull pk = (ull)f2bf(sv[ct][0] * inv)
               | ((ull)f2bf(sv[ct][1] * inv) << 16)
               | ((ull)f2bf(sv[ct][2] * inv) << 32)
               | ((ull)f2bf(sv[ct][3] * inv) << 48);
        unsigned byte = (unsigned)(rg * 16 + q) * 2048u + (((unsigned)(key0 * 2)) ^ sw);
        *(ull*)((char*)P + byte) = pk;
    }
    __syncthreads();

    // V prefetch (2 kt-steps) before the store phase
    const char* vbase = (const char*)Vpack + ((size_t)bh << 17)
                      + (size_t)wk * 32 * 1024 + lane * 16;
    short8 v0a = *(const short8*)(vbase);
    short8 v1a = *(const short8*)(vbase + 1024);

    // coalesced nt attn store: wave w stores block-rows w*4..w*4+3 (1KB/instr)
    {
        const size_t aRow = ((size_t)bh * NQ_ + q0) * NK_;
        #pragma unroll
        for (int i = 0; i < 4; ++i) {
            const int r = w * 4 + i;
            const unsigned swr = (unsigned)(r & 7) << 4;
            #pragma unroll
            for (int j = 0; j < 4; ++j) {
                unsigned byte = (unsigned)r * 2048u
                              + (((unsigned)(j * 512 + lane * 8)) ^ swr);
                ull pk = *(const ull*)((const char*)P + byte);
                f32x4 o;
                o[0] = __builtin_bit_cast(float, (unsigned)((pk & 0xFFFFull) << 16));
                o[1] = __builtin_bit_cast(float, (unsigned)(((pk >> 16) & 0xFFFFull) << 16));
                o[2] = __builtin_bit_cast(float, (unsigned)(((pk >> 32) & 0xFFFFull) << 16));
                o[3] = __builtin_bit_cast(float, (unsigned)((pk >> 48) << 16));
                __builtin_nontemporal_store(o,
                    (f32x4*)&attnOut[aRow + (size_t)r * NK_ + j * 256 + lane * 4]);
            }
        }
    }

    // PV: rows of group rg x d-cols [16wk,16wk+16)
    f32x4 acc0 = {}, acc1 = {};
    const unsigned prow = (unsigned)(rg * 16 + q) * 2048u;
    #pragma unroll
    for (int kt = 0; kt < 16; ++kt) {
        short8 vb0 = v0a, vb1 = v1a;
        if (kt < 15) {
            v0a = *(const short8*)(vbase + (kt + 1) * 2048);
            v1a = *(const short8*)(vbase + (kt + 1) * 2048 + 1024);
        }
        const int kb = kt * 64;
        unsigned o0 = ((unsigned)((kb + q4 * 8) * 2)) ^ sw;
        unsigned o1 = ((unsigned)((kb + 32 + q4 * 8) * 2)) ^ sw;
        short8 pa0 = *(const short8*)((const char*)P + prow + o0);
        short8 pa1 = *(const short8*)((const char*)P + prow + o1);
        __builtin_amdgcn_s_setprio(1);
        acc0 = __builtin_amdgcn_mfma_f32_16x16x32_bf16(pa0, vb0, acc0, 0, 0, 0);
        acc1 = __builtin_amdgcn_mfma_f32_16x16x32_bf16(pa1, vb1, acc1, 0, 0, 0);
        __builtin_amdgcn_s_setprio(0);
    }
    #pragma unroll
    for (int r = 0; r < 4; ++r) {
        float o = acc0[r] + acc1[r];
        Ob[(size_t)(b * NQ_ + q0 + rg * 16 + q4 * 4 + r) * 512 + h * 64 + wk * 16 + q] = f2bf(o);
    }
}

// ---------------------------------------------------------------------------
extern "C" void kernel_launch(void* const* d_in, const int* in_sizes, int n_in,
                              void* d_out, int out_size, void* d_ws, size_t ws_size,
                              hipStream_t stream)
{
    (void)in_sizes; (void)n_in; (void)out_size; (void)ws_size;
    const float* x    = (const float*)d_in[0];
    const float* x_q  = (const float*)d_in[1];
    const float* w_q  = (const float*)d_in[2];
    const float* w_kv = (const float*)d_in[3];
    const float* w_p  = (const float*)d_in[4];
    const float* b_p  = (const float*)d_in[5];

    float* out   = (float*)d_out;
    float* attnO = out + (size_t)B_ * NQ_ * DM_;

    us* Wq_t  = (us*)d_ws;                  // 256K elems
    us* Wkv_t = Wq_t  + 262144;             // 512K
    us* Wp_t  = Wkv_t + 524288;             // 256K
    us* Qh    = Wp_t  + 262144;             // 2M
    us* Kp    = Qh    + 2097152;            // 2M
    us* Vp    = Kp    + 2097152;            // 2M
    us* Ob    = Vp    + 2097152;            // 2M  (~18.5 MB total)

    wprep<<<256, 256, 0, stream>>>(w_q, w_kv, w_p, Wq_t, Wkv_t, Wp_t);
    qkv128<<<dim3(4, 32, 3), 256, 0, stream>>>(x_q, x, Wq_t, Wkv_t, Qh, Kp, Vp);
    attn5<<<dim3(32, 8, 4), 512, 0, stream>>>(Qh, Kp, Vp, attnO, Ob);
    out128<<<dim3(8, 32), 256, 0, stream>>>(Ob, Wp_t, b_p, out);
}

// Round 10
// 81.907 us; speedup vs baseline: 1.0557x; 1.0119x over previous
//
#include <hip/hip_runtime.h>

#define B_   4
#define NQ_  1024
#define NK_  1024
#define H_   8
#define DM_  512

typedef unsigned short us;
typedef unsigned long long ull;
typedef __attribute__((ext_vector_type(8))) short  short8;
typedef __attribute__((ext_vector_type(4))) float  f32x4;
typedef __attribute__((ext_vector_type(4))) int    i32x4;
typedef __attribute__((address_space(3))) unsigned int       lds_u32;
typedef const __attribute__((address_space(1))) unsigned int gl_u32;

static __device__ __forceinline__ us f2bf(float f) {
    unsigned int u = __builtin_bit_cast(unsigned int, f);
    u += 0x7FFF + ((u >> 16) & 1);
    return (us)(u >> 16);
}

// ---------------------------------------------------------------------------
// wprep: weights f32[K][N] -> bf16 [N][K].  256 blocks.
// ---------------------------------------------------------------------------
__global__ __launch_bounds__(256) void wprep(
    const float* __restrict__ wq, const float* __restrict__ wkv,
    const float* __restrict__ wp,
    us* __restrict__ Wq_t, us* __restrict__ Wkv_t, us* __restrict__ Wp_t)
{
    const int t = blockIdx.x, tid = threadIdx.x;
    const float* src; us* dst; int k0, n0, N; const int K = 512;
    if (t < 64)       { src = wq;  dst = Wq_t;  N = 512;  k0 = (t >> 3) * 64;         n0 = (t & 7) * 64; }
    else if (t < 192) { src = wkv; dst = Wkv_t; N = 1024; k0 = ((t - 64) >> 4) * 64;  n0 = ((t - 64) & 15) * 64; }
    else              { src = wp;  dst = Wp_t;  N = 512;  k0 = ((t - 192) >> 3) * 64; n0 = ((t - 192) & 7) * 64; }

    __shared__ us T[64][72];
    #pragma unroll
    for (int i = 0; i < 4; ++i) {
        int s = tid + i * 256;
        int r = s >> 4, c4 = (s & 15) * 4;
        float4 v = *(const float4*)&src[(size_t)(k0 + r) * N + n0 + c4];
        T[r][c4 + 0] = f2bf(v.x); T[r][c4 + 1] = f2bf(v.y);
        T[r][c4 + 2] = f2bf(v.z); T[r][c4 + 3] = f2bf(v.w);
    }
    __syncthreads();
    #pragma unroll
    for (int i = 0; i < 2; ++i) {
        int s = tid + i * 256;
        int n = s >> 3, k8 = (s & 7) * 8;
        union { us u[8]; i32x4 v; } tmp;
        #pragma unroll
        for (int j = 0; j < 8; ++j) tmp.u[j] = T[k8 + j][n];
        *(i32x4*)&dst[(size_t)(n0 + n) * K + k0 + k8] = tmp.v;
    }
}

// ---------------------------------------------------------------------------
// 128x128 core (BK=64): reads As/Bs with XOR slot swizzle.
// ---------------------------------------------------------------------------
__device__ __forceinline__ void core128(const us* As, const us* Bs, int l, int w,
                                        f32x4 acc[4][4])
{
    const int wr = (w >> 1) * 64, wc = (w & 1) * 64;
    short8 af[4][2], bf_[4][2];
    #pragma unroll
    for (int rt = 0; rt < 4; ++rt) {
        int row = wr + rt * 16 + (l & 15);
        #pragma unroll
        for (int ks = 0; ks < 2; ++ks) {
            int slot = ks * 4 + (l >> 4);
            af[rt][ks] = *(const short8*)((const char*)As + row * 128 + ((slot ^ (row & 7)) * 16));
        }
    }
    #pragma unroll
    for (int ct = 0; ct < 4; ++ct) {
        int row = wc + ct * 16 + (l & 15);
        #pragma unroll
        for (int ks = 0; ks < 2; ++ks) {
            int slot = ks * 4 + (l >> 4);
            bf_[ct][ks] = *(const short8*)((const char*)Bs + row * 128 + ((slot ^ (row & 7)) * 16));
        }
    }
    #pragma unroll
    for (int ks = 0; ks < 2; ++ks)
        #pragma unroll
        for (int rt = 0; rt < 4; ++rt)
            #pragma unroll
            for (int ct = 0; ct < 4; ++ct)
                acc[rt][ct] = __builtin_amdgcn_mfma_f32_16x16x32_bf16(
                    af[rt][ks], bf_[ct][ks], acc[rt][ct], 0, 0, 0);
}

// ---------------------------------------------------------------------------
// 128x64-tile core (BK=64, 4 waves, wave = 64 rows x 32 cols).
// ---------------------------------------------------------------------------
__device__ __forceinline__ void core6432(const us* As, const us* Bs, int l, int w,
                                         f32x4 acc[4][2])
{
    const int wr = (w >> 1) * 64, wc = (w & 1) * 32;
    short8 af[4][2], bf_[2][2];
    #pragma unroll
    for (int rt = 0; rt < 4; ++rt) {
        int row = wr + rt * 16 + (l & 15);
        #pragma unroll
        for (int ks = 0; ks < 2; ++ks) {
            int slot = ks * 4 + (l >> 4);
            af[rt][ks] = *(const short8*)((const char*)As + row * 128 + ((slot ^ (row & 7)) * 16));
        }
    }
    #pragma unroll
    for (int ct = 0; ct < 2; ++ct) {
        int row = wc + ct * 16 + (l & 15);
        #pragma unroll
        for (int ks = 0; ks < 2; ++ks) {
            int slot = ks * 4 + (l >> 4);
            bf_[ct][ks] = *(const short8*)((const char*)Bs + row * 128 + ((slot ^ (row & 7)) * 16));
        }
    }
    #pragma unroll
    for (int ks = 0; ks < 2; ++ks)
        #pragma unroll
        for (int rt = 0; rt < 4; ++rt)
            #pragma unroll
            for (int ct = 0; ct < 2; ++ct)
                acc[rt][ct] = __builtin_amdgcn_mfma_f32_16x16x32_bf16(
                    af[rt][ks], bf_[ct][ks], acc[rt][ct], 0, 0, 0);
}

// ---------------------------------------------------------------------------
// Fused QKV GEMM: z=0 Qh(*0.125), z=1 Kpack, z=2 Vpack.  grid (4, 32, 3).
// ---------------------------------------------------------------------------
__global__ __launch_bounds__(256, 2) void qkv128(
    const float* __restrict__ x_q, const float* __restrict__ x,
    const us* __restrict__ Wq_t, const us* __restrict__ Wkv_t,
    us* __restrict__ Qh, us* __restrict__ Kpack, us* __restrict__ Vpack)
{
    const int z = blockIdx.z;
    const float* Af = z ? x : x_q;
    const us* Bt    = z ? Wkv_t : Wq_t;
    const int m0 = blockIdx.y * 128, n0 = blockIdx.x * 128;
    const int bn0 = n0 + (z == 2 ? 512 : 0);

    __shared__ us smem[16896];               // As 16KB | Bs 16KB ; T reuses all
    us* As = smem; us* Bs = smem + 8192;
    const int tid = threadIdx.x, l = tid & 63, w = tid >> 6;

    const int rr0 = w * 32 + (l >> 3);
    const int ss  = (l & 7) ^ ((l >> 3) & 7);
    const us* gB = Bt + (size_t)(bn0 + rr0) * 512 + ss * 8;
    const float* gA = Af + (size_t)(m0 + w * 32 + (l >> 4)) * 512 + (l & 15) * 4;

    f32x4 acc[4][4] = {};
    for (int k0 = 0; k0 < 512; k0 += 64) {
        #pragma unroll
        for (int i = 0; i < 4; ++i)
            __builtin_amdgcn_global_load_lds((gl_u32*)(gB + (size_t)i * 8 * 512 + k0),
                                             (lds_u32*)(Bs + (w * 32 + i * 8) * 64), 16, 0, 0);
        #pragma unroll
        for (int j = 0; j < 8; ++j) {
            float4 f = *(const float4*)(gA + (size_t)j * 4 * 512 + k0);
            int row = w * 32 + j * 4 + (l >> 4);
            ull pk = (ull)f2bf(f.x) | ((ull)f2bf(f.y) << 16)
                   | ((ull)f2bf(f.z) << 32) | ((ull)f2bf(f.w) << 48);
            int slot = (l & 15) >> 1, sub = l & 1;
            *(ull*)((char*)As + row * 128 + ((slot ^ (row & 7)) * 16) + sub * 8) = pk;
        }
        __syncthreads();
        core128(As, Bs, l, w, acc);
        __syncthreads();
    }

    const int wr = (w >> 1) * 64, wc = (w & 1) * 64;
    if (z == 0) {
        #pragma unroll
        for (int rt = 0; rt < 4; ++rt)
          #pragma unroll
          for (int ct = 0; ct < 4; ++ct)
            #pragma unroll
            for (int r = 0; r < 4; ++r) {
                int row = m0 + wr + rt * 16 + (l >> 4) * 4 + r;
                int col = n0 + wc + ct * 16 + (l & 15);
                int hh = col >> 6, d = col & 63;
                Qh[((size_t)((row >> 10) * H_ + hh) << 16) + (size_t)(row & 1023) * 64 + d]
                    = f2bf(acc[rt][ct][r] * 0.125f);
            }
    } else if (z == 1) {
        #pragma unroll
        for (int rt = 0; rt < 4; ++rt)
          #pragma unroll
          for (int ct = 0; ct < 4; ++ct)
            #pragma unroll
            for (int r = 0; r < 4; ++r) {
                int row = m0 + wr + rt * 16 + (l >> 4) * 4 + r;
                int col = n0 + wc + ct * 16 + (l & 15);
                int hh = col >> 6, d = col & 63;
                int bh = (row >> 10) * H_ + hh, tl = row & 1023;
                size_t byte = ((size_t)bh << 17) + (size_t)(tl >> 4) * 2048
                            + (size_t)(d >> 5) * 1024
                            + ((((d >> 3) & 3) * 16 + (tl & 15)) * 16) + (d & 7) * 2;
                *(us*)((char*)Kpack + byte) = f2bf(acc[rt][ct][r]);
            }
    } else {
        us* T = smem;                        // [128][132]
        #pragma unroll
        for (int rt = 0; rt < 4; ++rt)
          #pragma unroll
          for (int ct = 0; ct < 4; ++ct)
            #pragma unroll
            for (int r = 0; r < 4; ++r) {
                int rl = wr + rt * 16 + (l >> 4) * 4 + r;
                int cl = wc + ct * 16 + (l & 15);
                T[rl * 132 + cl] = f2bf(acc[rt][ct][r]);
            }
        __syncthreads();
        const int bb = m0 >> 10, tb = m0 & 1023;
        #pragma unroll
        for (int i = 0; i < 8; ++i) {
            int s = tid + i * 256;
            int col = s >> 4, r8 = (s & 15) * 8;
            union { us u[8]; i32x4 v; } tmp;
            #pragma unroll
            for (int j = 0; j < 8; ++j) tmp.u[j] = T[(r8 + j) * 132 + col];
            int gcol = n0 + col;
            int hh = gcol >> 6, d = gcol & 63;
            int bh = bb * H_ + hh;
            int tl0 = tb + r8;
            int dt = d >> 4, q = d & 15;
            int kt = tl0 >> 6, koff = tl0 & 63;
            int p = koff >> 5, q4 = (koff >> 3) & 3;
            size_t byte = ((size_t)bh << 17) + (size_t)((dt * 16 + kt) * 2 + p) * 1024
                        + (q4 * 16 + q) * 16;
            *(i32x4*)((char*)Vpack + byte) = tmp.v;
        }
    }
}

// ---------------------------------------------------------------------------
// out = Ob @ Wp_t^T + bias.  128x64 tile -> 256 blocks (full CU coverage).
// ---------------------------------------------------------------------------
__global__ __launch_bounds__(256, 2) void out128(
    const us* __restrict__ Ob, const us* __restrict__ Wp_t,
    const float* __restrict__ bias, float* __restrict__ C)
{
    __shared__ us As[128 * 64], Bs[64 * 64];
    const int tid = threadIdx.x, l = tid & 63, w = tid >> 6;
    const int m0 = blockIdx.y * 128, n0 = blockIdx.x * 64;

    const us* gA = Ob   + (size_t)(m0 + w * 32 + (l >> 3)) * 512 + (size_t)(((l & 7) ^ (l >> 3)) * 8);
    const us* gB = Wp_t + (size_t)(n0 + w * 8  + (l >> 3)) * 512 + (size_t)(((l & 7) ^ (l >> 3)) * 8);

    f32x4 acc[4][2] = {};
    for (int k0 = 0; k0 < 512; k0 += 64) {
        #pragma unroll
        for (int i = 0; i < 4; ++i)
            __builtin_amdgcn_global_load_lds((gl_u32*)(gA + (size_t)i * 8 * 512 + k0),
                                             (lds_u32*)(As + (w * 32 + i * 8) * 64), 16, 0, 0);
        #pragma unroll
        for (int i = 0; i < 2; ++i)
            __builtin_amdgcn_global_load_lds((gl_u32*)(gB + (size_t)i * 32 * 512 + k0),
                                             (lds_u32*)(Bs + (w * 8 + i * 32) * 64), 16, 0, 0);
        __syncthreads();
        core6432(As, Bs, l, w, acc);
        __syncthreads();
    }

    const int wr = (w >> 1) * 64, wc = (w & 1) * 32;
    #pragma unroll
    for (int rt = 0; rt < 4; ++rt)
      #pragma unroll
      for (int ct = 0; ct < 2; ++ct)
        #pragma unroll
        for (int r = 0; r < 4; ++r) {
            int row = m0 + wr + rt * 16 + (l >> 4) * 4 + r;
            int col = n0 + wc + ct * 16 + (l & 15);
            C[(size_t)row * 512 + col] = acc[rt][ct][r] + bias[col];
        }
}

// ---------------------------------------------------------------------------
// Attention v8: round-5 structure with fused ONE-round softmax reduction:
// each wave computes local row-max m_w and s_w = sum e^{x-m_w} in registers
// BEFORE any barrier; one (m,s) publish + one barrier; scale folds
// e^{m_w-mg}/tot into the existing per-element normalize multiply.
// 2 barriers total (was 3), exp overlaps QK^T drain.
// ---------------------------------------------------------------------------
__global__ __launch_bounds__(512, 4) void attn8(
    const us* __restrict__ Qhp, const us* __restrict__ Kpack, const us* __restrict__ Vpack,
    float* __restrict__ attnOut, us* __restrict__ Ob)
{
    const int tid = threadIdx.x, lane = tid & 63, w = tid >> 6;
    const int rg = w >> 2, wk = w & 3;
    const int p = blockIdx.x + 32 * blockIdx.y + 256 * blockIdx.z;
    const int g = (p & 7) + 8 * ((p >> 3) & 3);
    const int b = g >> 3, h = g & 7, q0 = (p >> 5) * 32;
    const int q = lane & 15, q4 = lane >> 4;
    const int bh = b * H_ + h;

    __shared__ us P[32 * 1024];              // 64 KB
    __shared__ float redM[2][4][16], redS[2][4][16];

    const us* qp = &Qhp[((size_t)bh << 16) + (size_t)(q0 + rg * 16 + q) * 64 + q4 * 8];
    short8 bq0 = *(const short8*)qp;
    short8 bq1 = *(const short8*)(qp + 32);

    const char* kb_base = (const char*)Kpack + ((size_t)bh << 17) + (size_t)wk * 16 * 2048 + lane * 16;

    f32x4 sv[16];
    #pragma unroll
    for (int ct = 0; ct < 16; ++ct) {
        const char* ka_ = kb_base + ct * 2048;
        short8 ka  = *(const short8*)ka_;
        short8 kb2 = *(const short8*)(ka_ + 1024);
        f32x4 a = {};
        a = __builtin_amdgcn_mfma_f32_16x16x32_bf16(ka, bq0, a, 0, 0, 0);
        a = __builtin_amdgcn_mfma_f32_16x16x32_bf16(kb2, bq1, a, 0, 0, 0);
        sv[ct] = a;
    }

    // wave-local row max (lanes q, q+16, q+32, q+48 share row q)
    float m = sv[0][0];
    #pragma unroll
    for (int ct = 0; ct < 16; ++ct)
        #pragma unroll
        for (int r = 0; r < 4; ++r) m = fmaxf(m, sv[ct][r]);
    m = fmaxf(m, __shfl_xor(m, 16));
    m = fmaxf(m, __shfl_xor(m, 32));

    // exp with local max + wave-local sum, all pre-barrier
    float s = 0.f;
    #pragma unroll
    for (int ct = 0; ct < 16; ++ct)
        #pragma unroll
        for (int r = 0; r < 4; ++r) {
            float e = __expf(sv[ct][r] - m);
            sv[ct][r] = e;
            s += e;
        }
    s += __shfl_xor(s, 16);
    s += __shfl_xor(s, 32);
    if (lane < 16) { redM[rg][wk][lane] = m; redS[rg][wk][lane] = s; }
    __syncthreads();

    // global max + rescaled total; fold e^{m-mg}/tot into one per-lane scale
    const float m0r = redM[rg][0][q], m1r = redM[rg][1][q],
                m2r = redM[rg][2][q], m3r = redM[rg][3][q];
    const float mg = fmaxf(fmaxf(m0r, m1r), fmaxf(m2r, m3r));
    const float tot = redS[rg][0][q] * __expf(m0r - mg)
                    + redS[rg][1][q] * __expf(m1r - mg)
                    + redS[rg][2][q] * __expf(m2r - mg)
                    + redS[rg][3][q] * __expf(m3r - mg);
    const float myscale = __expf(m - mg) / tot;

    const unsigned sw = (unsigned)(q & 7) << 4;
    #pragma unroll
    for (int ct = 0; ct < 16; ++ct) {
        const int key0 = wk * 256 + ct * 16 + q4 * 4;
        ull pk = (ull)f2bf(sv[ct][0] * myscale)
               | ((ull)f2bf(sv[ct][1] * myscale) << 16)
               | ((ull)f2bf(sv[ct][2] * myscale) << 32)
               | ((ull)f2bf(sv[ct][3] * myscale) << 48);
        unsigned byte = (unsigned)(rg * 16 + q) * 2048u + (((unsigned)(key0 * 2)) ^ sw);
        *(ull*)((char*)P + byte) = pk;
    }
    __syncthreads();

    // V prefetch (2 kt-steps) before the store phase
    const char* vbase = (const char*)Vpack + ((size_t)bh << 17)
                      + (size_t)wk * 32 * 1024 + lane * 16;
    short8 v0a = *(const short8*)(vbase);
    short8 v1a = *(const short8*)(vbase + 1024);

    // coalesced nt attn store: wave w stores block-rows w*4..w*4+3 (1KB/instr)
    {
        const size_t aRow = ((size_t)bh * NQ_ + q0) * NK_;
        #pragma unroll
        for (int i = 0; i < 4; ++i) {
            const int r = w * 4 + i;
            const unsigned swr = (unsigned)(r & 7) << 4;
            #pragma unroll
            for (int j = 0; j < 4; ++j) {
                unsigned byte = (unsigned)r * 2048u
                              + (((unsigned)(j * 512 + lane * 8)) ^ swr);
                ull pk = *(const ull*)((const char*)P + byte);
                f32x4 o;
                o[0] = __builtin_bit_cast(float, (unsigned)((pk & 0xFFFFull) << 16));
                o[1] = __builtin_bit_cast(float, (unsigned)(((pk >> 16) & 0xFFFFull) << 16));
                o[2] = __builtin_bit_cast(float, (unsigned)(((pk >> 32) & 0xFFFFull) << 16));
                o[3] = __builtin_bit_cast(float, (unsigned)((pk >> 48) << 16));
                __builtin_nontemporal_store(o,
                    (f32x4*)&attnOut[aRow + (size_t)r * NK_ + j * 256 + lane * 4]);
            }
        }
    }

    // PV: rows of group rg x d-cols [16wk,16wk+16)
    f32x4 acc0 = {}, acc1 = {};
    const unsigned prow = (unsigned)(rg * 16 + q) * 2048u;
    #pragma unroll
    for (int kt = 0; kt < 16; ++kt) {
        short8 vb0 = v0a, vb1 = v1a;
        if (kt < 15) {
            v0a = *(const short8*)(vbase + (kt + 1) * 2048);
            v1a = *(const short8*)(vbase + (kt + 1) * 2048 + 1024);
        }
        const int kb = kt * 64;
        unsigned o0 = ((unsigned)((kb + q4 * 8) * 2)) ^ sw;
        unsigned o1 = ((unsigned)((kb + 32 + q4 * 8) * 2)) ^ sw;
        short8 pa0 = *(const short8*)((const char*)P + prow + o0);
        short8 pa1 = *(const short8*)((const char*)P + prow + o1);
        __builtin_amdgcn_s_setprio(1);
        acc0 = __builtin_amdgcn_mfma_f32_16x16x32_bf16(pa0, vb0, acc0, 0, 0, 0);
        acc1 = __builtin_amdgcn_mfma_f32_16x16x32_bf16(pa1, vb1, acc1, 0, 0, 0);
        __builtin_amdgcn_s_setprio(0);
    }
    #pragma unroll
    for (int r = 0; r < 4; ++r) {
        float o = acc0[r] + acc1[r];
        Ob[(size_t)(b * NQ_ + q0 + rg * 16 + q4 * 4 + r) * 512 + h * 64 + wk * 16 + q] = f2bf(o);
    }
}

// ---------------------------------------------------------------------------
extern "C" void kernel_launch(void* const* d_in, const int* in_sizes, int n_in,
                              void* d_out, int out_size, void* d_ws, size_t ws_size,
                              hipStream_t stream)
{
    (void)in_sizes; (void)n_in; (void)out_size; (void)ws_size;
    const float* x    = (const float*)d_in[0];
    const float* x_q  = (const float*)d_in[1];
    const float* w_q  = (const float*)d_in[2];
    const float* w_kv = (const float*)d_in[3];
    const float* w_p  = (const float*)d_in[4];
    const float* b_p  = (const float*)d_in[5];

    float* out   = (float*)d_out;
    float* attnO = out + (size_t)B_ * NQ_ * DM_;

    us* Wq_t  = (us*)d_ws;                  // 256K elems
    us* Wkv_t = Wq_t  + 262144;             // 512K
    us* Wp_t  = Wkv_t + 524288;             // 256K
    us* Qh    = Wp_t  + 262144;             // 2M
    us* Kp    = Qh    + 2097152;            // 2M
    us* Vp    = Kp    + 2097152;            // 2M
    us* Ob    = Vp    + 2097152;            // 2M  (~18.5 MB total)

    wprep<<<256, 256, 0, stream>>>(w_q, w_kv, w_p, Wq_t, Wkv_t, Wp_t);
    qkv128<<<dim3(4, 32, 3), 256, 0, stream>>>(x_q, x, Wq_t, Wkv_t, Qh, Kp, Vp);
    attn8<<<dim3(32, 8, 4), 512, 0, stream>>>(Qh, Kp, Vp, attnO, Ob);
    out128<<<dim3(8, 32), 256, 0, stream>>>(Ob, Wp_t, b_p, out);
}